// Round 8
// baseline (1145.922 us; speedup 1.0000x reference)
//
#include <hip/hip_runtime.h>
#include <stdint.h>

// FCOS head, MI355X. Implicit-GEMM conv3x3 via bf16 MFMA (16x16x32), activations
// NHWC bf16, global_load_lds(16B) staging. K-loop: 3-buffer LDS ring with RAW
// s_barrier + explicit s_waitcnt vmcnt(N) (R5 structure). GN stats fused into
// conv epilogue (shuffle-reduce + atomicAdd). __launch_bounds__(256,3) pins
// 3 waves/SIMD (R7's regression was a register-pressure occupancy cliff);
// B/A staging addresses are u32 offsets off a uniform SGPR base to cut VGPRs.

typedef __attribute__((ext_vector_type(8))) short short8;
typedef __attribute__((ext_vector_type(4))) float floatx4;

__device__ __forceinline__ unsigned short f2bf(float f) {
  unsigned u = __float_as_uint(f);
  u = (u + 0x7FFFu + ((u >> 16) & 1u)) >> 16;   // RNE
  return (unsigned short)u;
}
__device__ __forceinline__ unsigned pk2(float a, float b) {
  return (unsigned)f2bf(a) | ((unsigned)f2bf(b) << 16);
}
__device__ __forceinline__ void async16(const void* g, void* l) {
  __builtin_amdgcn_global_load_lds(
      (const __attribute__((address_space(1))) unsigned int*)g,
      (__attribute__((address_space(3))) unsigned int*)l, 16, 0, 0);
}

// s_waitcnt imm16 (gfx9 enc): vmcnt[3:0]|[15:14], expcnt[6:4], lgkmcnt[11:8]
#define WAIT_VM4 0x0F74   // vmcnt(4), exp/lgkm unconstrained
#define WAIT_VM0 0x0F70   // vmcnt(0)

// level geometry (fixed by problem): W = 1<<lw, HW = 1<<(2lw)
__device__ const int d_lw[5]   = {7, 6, 5, 4, 3};
__device__ const int d_off[5]  = {0, 16384, 20480, 21504, 21760};
__device__ const int d_nt[5]   = {128, 32, 8, 2, 1};           // ceil(HW/128)
__device__ const int d_cumT[6] = {0, 1024, 1280, 1344, 1360, 1368}; // 8*nt per level
__device__ const int d_cumO[6] = {0, 512, 640, 672, 680, 684};      // 4*nt per level

// ---------------------------------------------------------------------------
// init: zero page (1536 B at ws+0, OOB source) + 3 stage stats arrays
__global__ void zpk(float* zp, float* stats) {
  for (int i = threadIdx.x; i < 384; i += 256) zp[i] = 0.f;
  for (int i = threadIdx.x; i < 1920; i += 256) stats[i] = 0.f;
}

// ---------------------------------------------------------------------------
// weight transform: fp32 [O][I][3][3] -> bf16 blocked [mt][cc][tap][cs][m][8]
// z: 0..2 cls_w0..2, 3..5 reg_w0..2, 6 cls_out(pad 80->128), 7 reg_out+ctr(pad 5->128)
__global__ __launch_bounds__(256) void wtrans(
    const float* __restrict__ c0, const float* __restrict__ c1, const float* __restrict__ c2,
    const float* __restrict__ r0, const float* __restrict__ r1, const float* __restrict__ r2,
    const float* __restrict__ cw, const float* __restrict__ rw, const float* __restrict__ tw,
    unsigned short* __restrict__ dst) {
  const int z = blockIdx.y;
  const int nel = (z < 6) ? 589824 : 294912;
  const int idx = blockIdx.x * 256 + threadIdx.x;
  if (idx >= nel) return;
  int tmp = idx;
  const int j = tmp & 7;   tmp >>= 3;
  const int m = tmp & 127; tmp >>= 7;
  const int cs = tmp & 3;  tmp >>= 2;
  const int t = tmp % 9;   tmp /= 9;     // tap inner
  const int cc = tmp & 7;  const int mt = tmp >> 3;
  const int o = mt * 128 + m;
  const int i = cc * 32 + cs * 8 + j;
  float v = 0.f;
  const float* srcs[6] = {c0, c1, c2, r0, r1, r2};
  if (z < 6)      v = srcs[z][((size_t)o * 256 + i) * 9 + t];
  else if (z == 6){ if (o < 80) v = cw[((size_t)o * 256 + i) * 9 + t]; }
  else            { if (o < 4)  v = rw[((size_t)o * 256 + i) * 9 + t];
                    else if (o == 4) v = tw[(size_t)i * 9 + t]; }
  const size_t base = (z < 6) ? (size_t)z * 589824
                              : (size_t)6 * 589824 + (size_t)(z - 6) * 294912;
  dst[base + idx] = f2bf(v);
}

// ---------------------------------------------------------------------------
// feature NCHW fp32 -> NHWC bf16 (64x64 LDS tile transpose)
__global__ __launch_bounds__(256) void feat_nhwc(
    const float* __restrict__ src, unsigned short* __restrict__ dst, int off, int HW) {
  __shared__ unsigned short tile[64][65];
  const int img = blockIdx.z, c0 = blockIdx.y * 64, p0 = blockIdx.x * 64;
  const float* s = src + ((size_t)img * 256 + c0) * HW + p0;
  const int tid = threadIdx.x;
#pragma unroll
  for (int i = 0; i < 4; i++) {
    const int cl = (tid >> 4) + i * 16, pl = (tid & 15) * 4;
    const float4 v = *(const float4*)(s + (size_t)cl * HW + pl);
    tile[cl][pl]     = f2bf(v.x);
    tile[cl][pl + 1] = f2bf(v.y);
    tile[cl][pl + 2] = f2bf(v.z);
    tile[cl][pl + 3] = f2bf(v.w);
  }
  __syncthreads();
  const int pl = tid >> 2, cseg = (tid & 3) * 16;
  unsigned ro[8];
#pragma unroll
  for (int k = 0; k < 8; k++)
    ro[k] = (unsigned)tile[cseg + 2 * k][pl] | ((unsigned)tile[cseg + 2 * k + 1][pl] << 16);
  unsigned short* dp = dst + ((size_t)img * 21824 + off + p0 + pl) * 256 + c0 + cseg;
  uint4 u0 = {ro[0], ro[1], ro[2], ro[3]};
  uint4 u1 = {ro[4], ro[5], ro[6], ro[7]};
  *(uint4*)dp = u0;
  *(uint4*)(dp + 8) = u1;
}

// ---------------------------------------------------------------------------
// conv3x3 implicit GEMM, 3-buffer LDS ring, raw barrier + fine vmcnt.
// mode 0: tower conv -> y (NHWC bf16, +bias) + fused GN partial stats.
// mode 1: output convs -> d_out [img][85][21824].
__global__ __launch_bounds__(256, 3) void conv_mfma(
    const char* __restrict__ wsb,
    unsigned long long xoff0, unsigned long long xoff1,   // tower input byte offsets (img0)
    unsigned long long woffA, unsigned long long woffB,   // weight set byte offsets
    unsigned short* __restrict__ y0, unsigned short* __restrict__ y1,
    const float* __restrict__ cb0, const float* __restrict__ cb1,
    float* __restrict__ out,
    const float* __restrict__ ob_cls, const float* __restrict__ ob_reg,
    const float* __restrict__ ob_ctr,
    float* __restrict__ stats_out, int mode) {
  __shared__ __align__(16) char smem[49152];   // 3 buffers x (A 8K | B 8K)
  const int tid = threadIdx.x;
  const int* cum = (mode == 0) ? d_cumT : d_cumO;
  int bid = blockIdx.x, lvl = 0;
  while (bid >= cum[lvl + 1]) ++lvl;
  int r = bid - cum[lvl];
  const int lw = d_lw[lvl], W = 1 << lw, HW = 1 << (2 * lw), poffl = d_off[lvl];
  const int ntc = d_nt[lvl];
  const int nt = r % ntc; r /= ntc;
  int mt = 0;
  if (mode == 0) { mt = r & 1; r >>= 1; }
  const int img = r & 1, tower = r >> 1;

  const unsigned xoff = (unsigned)((tower ? xoff1 : xoff0) + (size_t)img * 21824 * 512);
  const unsigned woff = (unsigned)((tower ? woffB : woffA) + (size_t)mt * 589824);

  // this thread's staged B position (slot n = tid&127, csegs tid>>7 and +2)
  const int n = tid & 127;
  const int p = nt * 128 + n;
  const bool pv = p < HW;
  const int h = p >> lw, w = p & (W - 1);
  const unsigned cs0 = (unsigned)((tid >> 7) * 16);   // byte offset of first cseg

  // per-tap B row u32 offsets (zero page at ws+0 for OOB / padding)
  unsigned tbo[9];
#pragma unroll
  for (int t = 0; t < 9; t++) {
    const int rr = h + t / 3 - 1, cx = w + t % 3 - 1;
    const bool v = pv && rr >= 0 && rr < W && cx >= 0 && cx < W;
    tbo[t] = v ? (xoff + (unsigned)(poffl + rr * W + cx) * 512u + cs0) : cs0;
  }

  const unsigned a_off = woff + (unsigned)tid * 16u;   // A panel, this thread's slot
  char* l_tid = smem + tid * 16;

  const int lane = tid & 63, q = lane >> 4, lr = lane & 15;
  const int wv = tid >> 6, wm = wv >> 1, wn = wv & 1;
  int aoff[4], boff[4];
#pragma unroll
  for (int i = 0; i < 4; i++) {
    aoff[i] = ((q << 7) + wm * 64 + i * 16 + lr) << 4;
    boff[i] = (((q << 7) + wn * 64 + i * 16 + lr) << 4) + 8192;
  }

  floatx4 acc[4][4];
#pragma unroll
  for (int i = 0; i < 4; i++)
#pragma unroll
    for (int j = 0; j < 4; j++) acc[i][j] = (floatx4){0.f, 0.f, 0.f, 0.f};

  // stage unit IT into buffer BUF: A 2 cells, B 2 cells (imm-folded offsets)
#define STAGE(BUF, IT, TN, CCN)                                               \
  {                                                                           \
    char* la_ = l_tid + (BUF) * 16384;                                        \
    const char* ap_ = wsb + (size_t)(a_off + (unsigned)(IT) * 8192u);         \
    async16(ap_, la_);                                                        \
    const char* ap2_ = wsb + (size_t)(a_off + ((unsigned)(IT) * 8192u + 4096u)); \
    async16(ap2_, la_ + 4096);                                                \
    const char* bp_ = wsb + (size_t)tbo[TN];                                  \
    async16(bp_ + (CCN) * 64, la_ + 8192);                                    \
    async16(bp_ + (CCN) * 64 + 32, la_ + 12288);                              \
  }

  // K order: it = cc*9 + t (cc outer 0..7, tap inner 0..8). Unit it:
  // Per unit: waitcnt vmcnt(4) [stage(it) done, stage(it+1) in flight],
  // raw s_barrier, issue stage(it+2), consume buffer it%3.
#define UNIT(CC, U, WIMM)                                                     \
  {                                                                           \
    const int it_ = (CC) * 9 + (U);                                           \
    __builtin_amdgcn_s_waitcnt(WIMM);                                         \
    __builtin_amdgcn_s_barrier();                                             \
    asm volatile("" ::: "memory");                                            \
    if (it_ + 2 < 72) {                                                       \
      const int nu_ = (U) + 2;                                                \
      STAGE((nu_ % 3), it_ + 2, nu_ % 9, (CC) + nu_ / 9)                      \
    }                                                                         \
    asm volatile("" ::: "memory");                                            \
    const int sb_ = ((U) % 3) * 16384;                                        \
    short8 af[4], bfr[4];                                                     \
    _Pragma("unroll")                                                         \
    for (int i = 0; i < 4; i++) {                                             \
      af[i] = *(const short8*)(smem + sb_ + aoff[i]);                         \
      bfr[i] = *(const short8*)(smem + sb_ + boff[i]);                        \
    }                                                                         \
    _Pragma("unroll")                                                         \
    for (int i = 0; i < 4; i++)                                               \
      _Pragma("unroll")                                                       \
      for (int j = 0; j < 4; j++)                                             \
        acc[i][j] = __builtin_amdgcn_mfma_f32_16x16x32_bf16(af[i], bfr[j],    \
                                                            acc[i][j], 0, 0, 0); \
  }

  // prologue: stage units 0 and 1 into buffers 0 and 1
  STAGE(0, 0, 0, 0)
  STAGE(1, 1, 1, 0)

  for (int cc = 0; cc < 7; ++cc) {
#pragma unroll
    for (int u = 0; u < 9; ++u) UNIT(cc, u, WAIT_VM4)
  }
  // cc = 7 peeled: last 2 units have no younger loads to leave in flight
  UNIT(7, 0, WAIT_VM4) UNIT(7, 1, WAIT_VM4) UNIT(7, 2, WAIT_VM4)
  UNIT(7, 3, WAIT_VM4) UNIT(7, 4, WAIT_VM4) UNIT(7, 5, WAIT_VM4)
  UNIT(7, 6, WAIT_VM4) UNIT(7, 7, WAIT_VM0) UNIT(7, 8, WAIT_VM0)
#undef UNIT
#undef STAGE

  if (mode == 0) {
    unsigned short* y = (tower ? y1 : y0) + (size_t)img * 21824 * 256;
    const float* cb = tower ? cb1 : cb0;
    float gs[4] = {0.f, 0.f, 0.f, 0.f}, gq[4] = {0.f, 0.f, 0.f, 0.f};
#pragma unroll
    for (int j = 0; j < 4; j++) {
      const int pp = nt * 128 + wn * 64 + j * 16 + lr;
      if (pp >= HW) continue;
      unsigned short* yr = y + (size_t)(poffl + pp) * 256;
#pragma unroll
      for (int i = 0; i < 4; i++) {
        const int c = mt * 128 + wm * 64 + i * 16 + (q << 2);
        const float4 b4 = *(const float4*)(cb + c);
        floatx4 a = acc[i][j];
        const float vx = a.x + b4.x, vy = a.y + b4.y;
        const float vz = a.z + b4.z, vw = a.w + b4.w;
        gs[i] += (vx + vy) + (vz + vw);
        gq[i] += (vx * vx + vy * vy) + (vz * vz + vw * vw);
        uint2 u;
        u.x = pk2(vx, vy);
        u.y = pk2(vz, vw);
        *(uint2*)(yr + c) = u;
      }
    }
    // fused GN partial stats: group of fragment i is mt*8 + wm*4 + i (16 ch);
    // full-wave shuffle reduce, lane 0 atomics (16/block, trivial contention).
    const int tz = tower * 2 + img;
#pragma unroll
    for (int i = 0; i < 4; i++) {
      float s = gs[i], q2 = gq[i];
#pragma unroll
      for (int o2 = 32; o2 > 0; o2 >>= 1) {
        s += __shfl_down(s, o2);
        q2 += __shfl_down(q2, o2);
      }
      if (lane == 0) {
        const int g = mt * 8 + wm * 4 + i;
        float* st = stats_out + (((tz * 5 + lvl) * 16 + g) << 1);
        atomicAdd(st, s);
        atomicAdd(st + 1, q2);
      }
    }
  } else {
#pragma unroll
    for (int j = 0; j < 4; j++) {
      const int pp = nt * 128 + wn * 64 + j * 16 + lr;
      if (pp >= HW) continue;
      const size_t gp = (size_t)poffl + pp;
#pragma unroll
      for (int i = 0; i < 4; i++) {
        const int m0 = wm * 64 + i * 16 + (q << 2);
        floatx4 a = acc[i][j];
#pragma unroll
        for (int k2 = 0; k2 < 4; k2++) {
          const int m = m0 + k2;
          const float v = a[k2];
          if (tower == 0) {
            if (m < 80) out[((size_t)img * 85 + m) * 21824 + gp] = v + ob_cls[m];
          } else {
            if (m < 4)
              out[((size_t)img * 85 + 80 + m) * 21824 + gp] = fmaxf(v + ob_reg[m], 0.f);
            else if (m == 4)
              out[((size_t)img * 85 + 84) * 21824 + gp] = v + ob_ctr[0];
          }
        }
      }
    }
  }
}

// ---------------------------------------------------------------------------
// GN apply + affine + ReLU + bf16 cast: Y -> X (both towers/images flat).
__global__ __launch_bounds__(256) void gn_apply(
    const unsigned short* __restrict__ ybase, unsigned short* __restrict__ xbase,
    const float* __restrict__ stats,
    const float* __restrict__ g0, const float* __restrict__ b0,
    const float* __restrict__ g1, const float* __restrict__ b1) {
  const size_t slot = (size_t)blockIdx.x * 256 + threadIdx.x;
  const size_t e = slot * 8;
  const int c = (int)(e & 255);
  const size_t pg = e >> 8;
  const int gpos = (int)(pg % 21824);
  const int ti = (int)(pg / 21824);
  const int img = ti & 1, tower = ti >> 1;
  const int lvl = (gpos >= 16384) + (gpos >= 20480) + (gpos >= 21504) + (gpos >= 21760);
  const int grp = c >> 4;
  const float* st = stats + ((((tower * 2 + img) * 5 + lvl) * 16 + grp) * 2);
  const float cnt = (float)(16 << (2 * d_lw[lvl]));
  const float mean = st[0] / cnt;
  const float var = st[1] / cnt - mean * mean;
  const float rstd = rsqrtf(var + 1e-5f);
  const float* gam = (tower ? g1 : g0) + c;
  const float* bet = (tower ? b1 : b0) + c;
  uint4 d = *(const uint4*)(ybase + e);
  unsigned uu[4] = {d.x, d.y, d.z, d.w};
  unsigned ro[4];
#pragma unroll
  for (int k = 0; k < 4; k++) {
    float f0 = __uint_as_float(uu[k] << 16);
    float f1 = __uint_as_float(uu[k] & 0xFFFF0000u);
    float o0 = fmaxf((f0 - mean) * rstd * gam[2 * k] + bet[2 * k], 0.f);
    float o1 = fmaxf((f1 - mean) * rstd * gam[2 * k + 1] + bet[2 * k + 1], 0.f);
    ro[k] = (unsigned)f2bf(o0) | ((unsigned)f2bf(o1) << 16);
  }
  uint4 od = {ro[0], ro[1], ro[2], ro[3]};
  *(uint4*)(xbase + e) = od;
}

// ---------------------------------------------------------------------------
extern "C" void kernel_launch(void* const* d_in, const int* in_sizes, int n_in,
                              void* d_out, int out_size, void* d_ws, size_t ws_size,
                              hipStream_t stream) {
  (void)in_sizes; (void)n_in; (void)out_size; (void)ws_size;
  char* ws = (char*)d_ws;
  unsigned short* wblk = (unsigned short*)(ws + 2048);      // 8,257,536 B
  const size_t WSET_T = 1179648;                            // bytes per tower set
  const size_t WSET_O = 589824;                             // bytes per out set
  const size_t WOFF = 2048;
  const size_t XFEAT_OFF = WOFF + 6 * WSET_T + 2 * WSET_O;
  const size_t XSZ = (size_t)2 * 21824 * 256 * 2;           // 22,347,776 B
  const size_t XC_OFF = XFEAT_OFF + XSZ;
  const size_t XR_OFF = XC_OFF + XSZ;
  char* pXfeat = ws + XFEAT_OFF;
  char* pX = ws + XC_OFF;
  char* pY = ws + XR_OFF + XSZ;
  float* stats = (float*)(pY + 2 * XSZ);                    // 3 stages x 640 floats

  zpk<<<1, 256, 0, stream>>>((float*)ws, stats);
  wtrans<<<dim3(2304, 8), 256, 0, stream>>>(
      (const float*)d_in[5], (const float*)d_in[9], (const float*)d_in[13],
      (const float*)d_in[17], (const float*)d_in[21], (const float*)d_in[25],
      (const float*)d_in[29], (const float*)d_in[31], (const float*)d_in[33], wblk);
  const int HWs[5] = {16384, 4096, 1024, 256, 64};
  const int OFFs[5] = {0, 16384, 20480, 21504, 21760};
  for (int l = 0; l < 5; l++)
    feat_nhwc<<<dim3(HWs[l] / 64, 4, 2), 256, 0, stream>>>(
        (const float*)d_in[l], (unsigned short*)pXfeat, OFFs[l], HWs[l]);

  unsigned short* xc = (unsigned short*)pX;
  unsigned short* yc = (unsigned short*)pY;
  unsigned short* yr = (unsigned short*)(pY + XSZ);

  for (int s = 0; s < 3; s++) {
    const unsigned long long in0 = s ? (unsigned long long)XC_OFF : (unsigned long long)XFEAT_OFF;
    const unsigned long long in1 = s ? (unsigned long long)XR_OFF : (unsigned long long)XFEAT_OFF;
    const unsigned long long wc = WOFF + (size_t)s * WSET_T;
    const unsigned long long wr = WOFF + (size_t)(3 + s) * WSET_T;
    float* st_s = stats + (size_t)s * 640;
    conv_mfma<<<1368, 256, 0, stream>>>(
        (const char*)ws, in0, in1, wc, wr, yc, yr,
        (const float*)d_in[6 + 4 * s], (const float*)d_in[18 + 4 * s],
        nullptr, nullptr, nullptr, nullptr, st_s, 0);
    gn_apply<<<21824, 256, 0, stream>>>(
        (const unsigned short*)pY, (unsigned short*)pX, st_s,
        (const float*)d_in[7 + 4 * s], (const float*)d_in[8 + 4 * s],
        (const float*)d_in[19 + 4 * s], (const float*)d_in[20 + 4 * s]);
  }
  const unsigned long long wo_c = WOFF + 6 * WSET_T;
  const unsigned long long wo_r = wo_c + WSET_O;
  conv_mfma<<<684, 256, 0, stream>>>(
      (const char*)ws, (unsigned long long)XC_OFF, (unsigned long long)XR_OFF,
      wo_c, wo_r, nullptr, nullptr, nullptr, nullptr,
      (float*)d_out, (const float*)d_in[30], (const float*)d_in[32],
      (const float*)d_in[34], nullptr, 1);
}

// Round 9
// 840.259 us; speedup vs baseline: 1.3638x; 1.3638x over previous
//
#include <hip/hip_runtime.h>
#include <stdint.h>

// FCOS head, MI355X. Implicit-GEMM conv3x3 via bf16 MFMA (16x16x32), activations
// NHWC bf16, global_load_lds(16B) staging. K-loop: R5 3-buffer LDS ring with RAW
// s_barrier + explicit s_waitcnt vmcnt(N) (measured local optimum, 163 us).
// gn_stats rewritten as coalesced streaming reduction; 5 feat_nhwc launches merged.

typedef __attribute__((ext_vector_type(8))) short short8;
typedef __attribute__((ext_vector_type(4))) float floatx4;

__device__ __forceinline__ unsigned short f2bf(float f) {
  unsigned u = __float_as_uint(f);
  u = (u + 0x7FFFu + ((u >> 16) & 1u)) >> 16;   // RNE
  return (unsigned short)u;
}
__device__ __forceinline__ unsigned pk2(float a, float b) {
  return (unsigned)f2bf(a) | ((unsigned)f2bf(b) << 16);
}
__device__ __forceinline__ void async16(const void* g, void* l) {
  __builtin_amdgcn_global_load_lds(
      (const __attribute__((address_space(1))) unsigned int*)g,
      (__attribute__((address_space(3))) unsigned int*)l, 16, 0, 0);
}

// s_waitcnt imm16 (gfx9 enc): vmcnt[3:0]|[15:14], expcnt[6:4], lgkmcnt[11:8]
#define WAIT_VM4 0x0F74   // vmcnt(4), exp/lgkm unconstrained
#define WAIT_VM0 0x0F70   // vmcnt(0)

// level geometry (fixed by problem): W = 1<<lw, HW = 1<<(2lw)
__device__ const int d_lw[5]   = {7, 6, 5, 4, 3};
__device__ const int d_off[5]  = {0, 16384, 20480, 21504, 21760};
__device__ const int d_nt[5]   = {128, 32, 8, 2, 1};           // ceil(HW/128)
__device__ const int d_cumT[6] = {0, 1024, 1280, 1344, 1360, 1368}; // 8*nt per level
__device__ const int d_cumO[6] = {0, 512, 640, 672, 680, 684};      // 4*nt per level
__device__ const int d_cumS[6] = {0, 256, 320, 336, 340, 341};      // HW/64 tiles/chunks

// ---------------------------------------------------------------------------
// init: zero page (1536 B, OOB source for global_load_lds) + 3 stage stats
// arrays (3 x 640 floats) -- ws is re-poisoned to 0xAA before every launch.
__global__ void zpk(float* zp, float* stats) {
  for (int i = threadIdx.x; i < 384; i += 256) zp[i] = 0.f;
  for (int i = threadIdx.x; i < 1920; i += 256) stats[i] = 0.f;
}

// ---------------------------------------------------------------------------
// weight transform: fp32 [O][I][3][3] -> bf16 blocked [mt][cc][tap][cs][m][8]
// z: 0..2 cls_w0..2, 3..5 reg_w0..2, 6 cls_out(pad 80->128), 7 reg_out+ctr(pad 5->128)
__global__ __launch_bounds__(256) void wtrans(
    const float* __restrict__ c0, const float* __restrict__ c1, const float* __restrict__ c2,
    const float* __restrict__ r0, const float* __restrict__ r1, const float* __restrict__ r2,
    const float* __restrict__ cw, const float* __restrict__ rw, const float* __restrict__ tw,
    unsigned short* __restrict__ dst) {
  const int z = blockIdx.y;
  const int nel = (z < 6) ? 589824 : 294912;
  const int idx = blockIdx.x * 256 + threadIdx.x;
  if (idx >= nel) return;
  int tmp = idx;
  const int j = tmp & 7;   tmp >>= 3;
  const int m = tmp & 127; tmp >>= 7;
  const int cs = tmp & 3;  tmp >>= 2;
  const int t = tmp % 9;   tmp /= 9;     // tap inner
  const int cc = tmp & 7;  const int mt = tmp >> 3;
  const int o = mt * 128 + m;
  const int i = cc * 32 + cs * 8 + j;
  float v = 0.f;
  const float* srcs[6] = {c0, c1, c2, r0, r1, r2};
  if (z < 6)      v = srcs[z][((size_t)o * 256 + i) * 9 + t];
  else if (z == 6){ if (o < 80) v = cw[((size_t)o * 256 + i) * 9 + t]; }
  else            { if (o < 4)  v = rw[((size_t)o * 256 + i) * 9 + t];
                    else if (o == 4) v = tw[(size_t)i * 9 + t]; }
  const size_t base = (z < 6) ? (size_t)z * 589824
                              : (size_t)6 * 589824 + (size_t)(z - 6) * 294912;
  dst[base + idx] = f2bf(v);
}

// ---------------------------------------------------------------------------
// feature NCHW fp32 -> NHWC bf16 (64x64 LDS tile transpose), all 5 levels in
// one dispatch: blockIdx.x = global position tile (d_cumS), y = ch quarter, z = img.
__global__ __launch_bounds__(256) void feat_nhwc(
    const float* __restrict__ s0, const float* __restrict__ s1,
    const float* __restrict__ s2, const float* __restrict__ s3,
    const float* __restrict__ s4, unsigned short* __restrict__ dst) {
  __shared__ unsigned short tile[64][65];
  int bx = blockIdx.x, lvl = 0;
  while (bx >= d_cumS[lvl + 1]) ++lvl;
  const int HW = 1 << (2 * d_lw[lvl]), off = d_off[lvl];
  const float* srcs[5] = {s0, s1, s2, s3, s4};
  const float* src = srcs[lvl];
  const int img = blockIdx.z, c0 = blockIdx.y * 64, p0 = (bx - d_cumS[lvl]) * 64;
  const float* s = src + ((size_t)img * 256 + c0) * HW + p0;
  const int tid = threadIdx.x;
#pragma unroll
  for (int i = 0; i < 4; i++) {
    const int cl = (tid >> 4) + i * 16, pl = (tid & 15) * 4;
    const float4 v = *(const float4*)(s + (size_t)cl * HW + pl);
    tile[cl][pl]     = f2bf(v.x);
    tile[cl][pl + 1] = f2bf(v.y);
    tile[cl][pl + 2] = f2bf(v.z);
    tile[cl][pl + 3] = f2bf(v.w);
  }
  __syncthreads();
  const int pl = tid >> 2, cseg = (tid & 3) * 16;
  unsigned ro[8];
#pragma unroll
  for (int k = 0; k < 8; k++)
    ro[k] = (unsigned)tile[cseg + 2 * k][pl] | ((unsigned)tile[cseg + 2 * k + 1][pl] << 16);
  unsigned short* dp = dst + ((size_t)img * 21824 + off + p0 + pl) * 256 + c0 + cseg;
  uint4 u0 = {ro[0], ro[1], ro[2], ro[3]};
  uint4 u1 = {ro[4], ro[5], ro[6], ro[7]};
  *(uint4*)dp = u0;
  *(uint4*)(dp + 8) = u1;
}

// ---------------------------------------------------------------------------
// conv3x3 implicit GEMM, 3-buffer LDS ring, raw barrier + fine vmcnt (R5).
// mode 0: tower conv -> y (NHWC bf16, +bias). mode 1: output convs -> d_out.
__global__ __launch_bounds__(256) void conv_mfma(
    const unsigned short* __restrict__ xin0, const unsigned short* __restrict__ xin1,
    const unsigned short* __restrict__ wA, const unsigned short* __restrict__ wB,
    unsigned short* __restrict__ y0, unsigned short* __restrict__ y1,
    const float* __restrict__ cb0, const float* __restrict__ cb1,
    float* __restrict__ out,
    const float* __restrict__ ob_cls, const float* __restrict__ ob_reg, const float* __restrict__ ob_ctr,
    const unsigned short* __restrict__ zp, int mode) {
  __shared__ __align__(16) char smem[49152];   // 3 buffers x (A 8K | B 8K)
  const int tid = threadIdx.x;
  const int* cum = (mode == 0) ? d_cumT : d_cumO;
  int bid = blockIdx.x, lvl = 0;
  while (bid >= cum[lvl + 1]) ++lvl;
  int r = bid - cum[lvl];
  const int lw = d_lw[lvl], W = 1 << lw, HW = 1 << (2 * lw), poffl = d_off[lvl];
  const int ntc = d_nt[lvl];
  const int nt = r % ntc; r /= ntc;
  int mt = 0;
  if (mode == 0) { mt = r & 1; r >>= 1; }
  const int img = r & 1, tower = r >> 1;

  const unsigned short* xin = (tower ? xin1 : xin0) + (size_t)img * 21824 * 256;
  const unsigned short* wset = tower ? wB : wA;

  // this thread's staged B position (slot n = tid&127, csegs tid>>7 and +2)
  const int n = tid & 127;
  const int p = nt * 128 + n;
  const bool pv = p < HW;
  const int h = p >> lw, w = p & (W - 1);
  const int cs0 = (tid >> 7) * 16;   // byte offset of first cseg

  // per-tap B base pointers (zero page for OOB / padding), statically indexed below
  const char* tb[9];
#pragma unroll
  for (int t = 0; t < 9; t++) {
    const int rr = h + t / 3 - 1, cx = w + t % 3 - 1;
    const bool v = pv && rr >= 0 && rr < W && cx >= 0 && cx < W;
    tb[t] = v ? (const char*)(xin + (size_t)(poffl + rr * W + cx) * 256) + cs0
              : (const char*)zp + cs0;
  }

  const char* abase = (const char*)wset + (size_t)mt * 589824;  // bytes per mt panel
  const char* a_tid = abase + (size_t)tid * 16;
  char* l_tid = smem + tid * 16;

  const int lane = tid & 63, q = lane >> 4, lr = lane & 15;
  const int wv = tid >> 6, wm = wv >> 1, wn = wv & 1;
  int aoff[4], boff[4];
#pragma unroll
  for (int i = 0; i < 4; i++) {
    aoff[i] = ((q << 7) + wm * 64 + i * 16 + lr) << 4;
    boff[i] = (((q << 7) + wn * 64 + i * 16 + lr) << 4) + 8192;
  }

  floatx4 acc[4][4];
#pragma unroll
  for (int i = 0; i < 4; i++)
#pragma unroll
    for (int j = 0; j < 4; j++) acc[i][j] = (floatx4){0.f, 0.f, 0.f, 0.f};

  // K order: it = cc*9 + t (cc outer 0..7, tap inner 0..8). Unit it:
  // A (8KB) at a_tid + it*8192; B at tb[it%9] + (it/9)*64. Buffer = it%3.
  // Per unit: waitcnt vmcnt(4) [stage(it) done, stage(it+1) in flight],
  // raw s_barrier, issue stage(it+2), consume buffer it%3.
#define UNIT(CC, U, WIMM)                                                     \
  {                                                                           \
    const int it_ = (CC) * 9 + (U);                                           \
    __builtin_amdgcn_s_waitcnt(WIMM);                                         \
    __builtin_amdgcn_s_barrier();                                             \
    asm volatile("" ::: "memory");                                            \
    if (it_ + 2 < 72) {                                                       \
      const int nu_ = (U) + 2;                                                \
      const int tn_ = nu_ % 9;            /* compile-time */                  \
      const int ccn_ = (CC) + nu_ / 9;                                        \
      char* la_ = l_tid + (nu_ % 3) * 16384;                                  \
      const char* ap_ = a_tid + (size_t)(it_ + 2) * 8192;                     \
      async16(ap_, la_);                                                      \
      async16(ap_ + 4096, la_ + 4096);                                        \
      const char* bp_ = tb[tn_] + ccn_ * 64;                                  \
      async16(bp_, la_ + 8192);                                               \
      async16(bp_ + 32, la_ + 12288);                                         \
    }                                                                         \
    asm volatile("" ::: "memory");                                            \
    const int sb_ = ((U) % 3) * 16384;                                        \
    short8 af[4], bfr[4];                                                     \
    _Pragma("unroll")                                                         \
    for (int i = 0; i < 4; i++) {                                             \
      af[i] = *(const short8*)(smem + sb_ + aoff[i]);                         \
      bfr[i] = *(const short8*)(smem + sb_ + boff[i]);                        \
    }                                                                         \
    _Pragma("unroll")                                                         \
    for (int i = 0; i < 4; i++)                                               \
      _Pragma("unroll")                                                       \
      for (int j = 0; j < 4; j++)                                             \
        acc[i][j] = __builtin_amdgcn_mfma_f32_16x16x32_bf16(af[i], bfr[j],    \
                                                            acc[i][j], 0, 0, 0); \
  }

  // prologue: stage units 0 and 1 into buffers 0 and 1
  async16(a_tid, l_tid);
  async16(a_tid + 4096, l_tid + 4096);
  async16(tb[0], l_tid + 8192);
  async16(tb[0] + 32, l_tid + 12288);
  async16(a_tid + 8192, l_tid + 16384);
  async16(a_tid + 12288, l_tid + 20480);
  async16(tb[1], l_tid + 24576);
  async16(tb[1] + 32, l_tid + 28672);

  for (int cc = 0; cc < 7; ++cc) {
#pragma unroll
    for (int u = 0; u < 9; ++u) UNIT(cc, u, WAIT_VM4)
  }
  // cc = 7 peeled: last 2 units have no younger loads to leave in flight
  UNIT(7, 0, WAIT_VM4) UNIT(7, 1, WAIT_VM4) UNIT(7, 2, WAIT_VM4)
  UNIT(7, 3, WAIT_VM4) UNIT(7, 4, WAIT_VM4) UNIT(7, 5, WAIT_VM4)
  UNIT(7, 6, WAIT_VM4) UNIT(7, 7, WAIT_VM0) UNIT(7, 8, WAIT_VM0)
#undef UNIT

  if (mode == 0) {
    unsigned short* y = (tower ? y1 : y0) + (size_t)img * 21824 * 256;
    const float* cb = tower ? cb1 : cb0;
#pragma unroll
    for (int j = 0; j < 4; j++) {
      const int pp = nt * 128 + wn * 64 + j * 16 + lr;
      if (pp >= HW) continue;
      unsigned short* yr = y + (size_t)(poffl + pp) * 256;
#pragma unroll
      for (int i = 0; i < 4; i++) {
        const int c = mt * 128 + wm * 64 + i * 16 + (q << 2);
        const float4 b4 = *(const float4*)(cb + c);
        floatx4 a = acc[i][j];
        uint2 u;
        u.x = pk2(a.x + b4.x, a.y + b4.y);
        u.y = pk2(a.z + b4.z, a.w + b4.w);
        *(uint2*)(yr + c) = u;
      }
    }
  } else {
#pragma unroll
    for (int j = 0; j < 4; j++) {
      const int pp = nt * 128 + wn * 64 + j * 16 + lr;
      if (pp >= HW) continue;
      const size_t gp = (size_t)poffl + pp;
#pragma unroll
      for (int i = 0; i < 4; i++) {
        const int m0 = wm * 64 + i * 16 + (q << 2);
        floatx4 a = acc[i][j];
#pragma unroll
        for (int k2 = 0; k2 < 4; k2++) {
          const int m = m0 + k2;
          const float v = a[k2];
          if (tower == 0) {
            if (m < 80) out[((size_t)img * 85 + m) * 21824 + gp] = v + ob_cls[m];
          } else {
            if (m < 4)
              out[((size_t)img * 85 + 80 + m) * 21824 + gp] = fmaxf(v + ob_reg[m], 0.f);
            else if (m == 4)
              out[((size_t)img * 85 + 84) * 21824 + gp] = v + ob_ctr[0];
          }
        }
      }
    }
  }
}

// ---------------------------------------------------------------------------
// GN stats, coalesced streaming: block = (chunk within level, tz); each thread
// sweeps uint4s (8 ch, one group: slot = tid%32 fixed); wave shuffle + LDS
// reduce; 16 atomicAdd pairs per block into zpk-zeroed stats.
__global__ __launch_bounds__(256) void gn_stats(
    const unsigned short* __restrict__ y0, const unsigned short* __restrict__ y1,
    float* __restrict__ stats) {
  const int tz = blockIdx.z;
  const int tower = tz >> 1, img = tz & 1;
  int bx = blockIdx.x, lvl = 0;
  while (bx >= d_cumS[lvl + 1]) ++lvl;
  const int chunk = bx - d_cumS[lvl];
  const int off = d_off[lvl];
  const uint4* y = (const uint4*)((tower ? y1 : y0) + ((size_t)img * 21824 + off) * 256);
  const int tid = threadIdx.x;
  float s = 0.f, s2 = 0.f;
  const int e0 = chunk * 2048 + tid;   // 2048 uint4 per chunk (32 KB)
#pragma unroll
  for (int it = 0; it < 8; ++it) {
    const uint4 d = y[e0 + it * 256];
    unsigned uu[4] = {d.x, d.y, d.z, d.w};
#pragma unroll
    for (int k = 0; k < 4; k++) {
      const float f0 = __uint_as_float(uu[k] << 16);
      const float f1 = __uint_as_float(uu[k] & 0xFFFF0000u);
      s += f0 + f1;
      s2 += f0 * f0 + f1 * f1;
    }
  }
  // slot = tid%32 (8-ch block), group = slot>>1. Reduce lanes slot-aligned.
  s += __shfl_down(s, 32);
  s2 += __shfl_down(s2, 32);
  __shared__ float ls[4][32], lq[4][32];
  const int lane = tid & 63, wv = tid >> 6;
  if (lane < 32) { ls[wv][lane] = s; lq[wv][lane] = s2; }
  __syncthreads();
  if (tid < 32) {
    const float S = ls[0][tid] + ls[1][tid] + ls[2][tid] + ls[3][tid];
    const float Q = lq[0][tid] + lq[1][tid] + lq[2][tid] + lq[3][tid];
    ls[0][tid] = S; lq[0][tid] = Q;
  }
  __syncthreads();
  if (tid < 16) {
    float* st = stats + (((tz * 5 + lvl) * 16 + tid) << 1);
    atomicAdd(st, ls[0][2 * tid] + ls[0][2 * tid + 1]);
    atomicAdd(st + 1, lq[0][2 * tid] + lq[0][2 * tid + 1]);
  }
}

// ---------------------------------------------------------------------------
// GN apply + affine + ReLU + bf16 cast: Y -> X (both towers/images flat).
__global__ __launch_bounds__(256) void gn_apply(
    const unsigned short* __restrict__ ybase, unsigned short* __restrict__ xbase,
    const float* __restrict__ stats,
    const float* __restrict__ g0, const float* __restrict__ b0,
    const float* __restrict__ g1, const float* __restrict__ b1) {
  const size_t slot = (size_t)blockIdx.x * 256 + threadIdx.x;
  const size_t e = slot * 8;
  const int c = (int)(e & 255);
  const size_t pg = e >> 8;
  const int gpos = (int)(pg % 21824);
  const int ti = (int)(pg / 21824);
  const int img = ti & 1, tower = ti >> 1;
  const int lvl = (gpos >= 16384) + (gpos >= 20480) + (gpos >= 21504) + (gpos >= 21760);
  const int grp = c >> 4;
  const float* st = stats + ((((tower * 2 + img) * 5 + lvl) * 16 + grp) * 2);
  const float cnt = (float)(16 << (2 * d_lw[lvl]));
  const float mean = st[0] / cnt;
  const float var = st[1] / cnt - mean * mean;
  const float rstd = rsqrtf(var + 1e-5f);
  const float* gam = (tower ? g1 : g0) + c;
  const float* bet = (tower ? b1 : b0) + c;
  uint4 d = *(const uint4*)(ybase + e);
  unsigned uu[4] = {d.x, d.y, d.z, d.w};
  unsigned ro[4];
#pragma unroll
  for (int k = 0; k < 4; k++) {
    float f0 = __uint_as_float(uu[k] << 16);
    float f1 = __uint_as_float(uu[k] & 0xFFFF0000u);
    float o0 = fmaxf((f0 - mean) * rstd * gam[2 * k] + bet[2 * k], 0.f);
    float o1 = fmaxf((f1 - mean) * rstd * gam[2 * k + 1] + bet[2 * k + 1], 0.f);
    ro[k] = (unsigned)f2bf(o0) | ((unsigned)f2bf(o1) << 16);
  }
  uint4 od = {ro[0], ro[1], ro[2], ro[3]};
  *(uint4*)(xbase + e) = od;
}

// ---------------------------------------------------------------------------
extern "C" void kernel_launch(void* const* d_in, const int* in_sizes, int n_in,
                              void* d_out, int out_size, void* d_ws, size_t ws_size,
                              hipStream_t stream) {
  (void)in_sizes; (void)n_in; (void)out_size; (void)ws_size;
  char* ws = (char*)d_ws;
  unsigned short* zp = (unsigned short*)ws;                 // 1536 B zeros
  unsigned short* wblk = (unsigned short*)(ws + 2048);      // 8,257,536 B
  const size_t WSET_T = 1179648;                            // bytes per tower set
  const size_t WSET_O = 589824;                             // bytes per out set
  char* pXfeat = ws + 2048 + 6 * WSET_T + 2 * WSET_O;
  const size_t XSZ = (size_t)2 * 21824 * 256 * 2;           // 22,347,776 B
  char* pX = pXfeat + XSZ;                                  // 2 towers
  char* pY = pX + 2 * XSZ;                                  // 2 towers
  float* stats = (float*)(pY + 2 * XSZ);                    // 3 stages x 640 floats

  zpk<<<1, 256, 0, stream>>>((float*)zp, stats);
  wtrans<<<dim3(2304, 8), 256, 0, stream>>>(
      (const float*)d_in[5], (const float*)d_in[9], (const float*)d_in[13],
      (const float*)d_in[17], (const float*)d_in[21], (const float*)d_in[25],
      (const float*)d_in[29], (const float*)d_in[31], (const float*)d_in[33], wblk);
  feat_nhwc<<<dim3(341, 4, 2), 256, 0, stream>>>(
      (const float*)d_in[0], (const float*)d_in[1], (const float*)d_in[2],
      (const float*)d_in[3], (const float*)d_in[4], (unsigned short*)pXfeat);

  unsigned short* xc = (unsigned short*)pX;
  unsigned short* xr = (unsigned short*)(pX + XSZ);
  unsigned short* yc = (unsigned short*)pY;
  unsigned short* yr = (unsigned short*)(pY + XSZ);

  for (int s = 0; s < 3; s++) {
    const unsigned short* in0 = s ? xc : (unsigned short*)pXfeat;
    const unsigned short* in1 = s ? xr : (unsigned short*)pXfeat;
    const unsigned short* wc = wblk + (size_t)s * 589824;        // elem stride per set
    const unsigned short* wr = wblk + (size_t)(3 + s) * 589824;
    float* st_s = stats + (size_t)s * 640;
    conv_mfma<<<1368, 256, 0, stream>>>(
        in0, in1, wc, wr, yc, yr,
        (const float*)d_in[6 + 4 * s], (const float*)d_in[18 + 4 * s],
        nullptr, nullptr, nullptr, nullptr, zp, 0);
    gn_stats<<<dim3(341, 1, 4), 256, 0, stream>>>(yc, yr, st_s);
    gn_apply<<<21824, 256, 0, stream>>>(
        (const unsigned short*)pY, (unsigned short*)pX, st_s,
        (const float*)d_in[7 + 4 * s], (const float*)d_in[8 + 4 * s],
        (const float*)d_in[19 + 4 * s], (const float*)d_in[20 + 4 * s]);
  }
  const unsigned short* wo_c = wblk + (size_t)6 * 589824;
  const unsigned short* wo_r = wo_c + 294912;
  conv_mfma<<<684, 256, 0, stream>>>(
      xc, xr, wo_c, wo_r, nullptr, nullptr, nullptr, nullptr,
      (float*)d_out, (const float*)d_in[30], (const float*)d_in[32],
      (const float*)d_in[34], zp, 1);
}